// Round 1
// 263.276 us; speedup vs baseline: 1.0689x; 1.0689x over previous
//
#include <hip/hip_runtime.h>
#include <hip/hip_bf16.h>
#include <math.h>

#define IN_F  1024
#define OUT_F 1024
#define BATCH 8192
#define KD2   7168             // 1024*6 spline (j=2..7) + 1024 silu
#define KHALF 3584             // K per split-K half
#define NKS   56               // K-steps (BK=64) per half
#define HTSH  8192             // shorts per 128x64 half-tile (16 KB)

typedef short short8  __attribute__((ext_vector_type(8)));
typedef short short4v __attribute__((ext_vector_type(4)));
typedef float f32x4   __attribute__((ext_vector_type(4)));

__device__ __forceinline__ short f2bf(float f) {
    __hip_bfloat16 h = __float2bfloat16(f);   // RNE
    return *reinterpret_cast<short*>(&h);
}

__device__ __forceinline__ float silu(float v) {
    return v / (1.0f + __expf(-v));
}

// Tiled layout: tile (rowblk, kh, ks, half) of 128 rows x 64 k, 16 KB each.
// Within a tile, shorts stored at row*64 + (col ^ ((row&7)<<3))  [T2 swizzle,
// pre-applied at pack time so GEMM staging is pure linear global_load_lds].
__device__ __forceinline__ size_t tile_off(int rowblk, int kh, int ks, int half) {
    return (((((size_t)rowblk * 2 + kh) * NKS + ks) * 2) + half) * (size_t)HTSH;
}

// 6 bases (j=2..7) for one x in [0,1): 4 nonzero at window offset ci-5 in {0,1,2}.
__device__ __forceinline__ void bases6(float xv, short* __restrict__ o) {
    const float s  = (xv + 2.2f) * 2.5f;     // (x - g0) / h
    const float cf = floorf(s);
    const int  off = (int)cf - 5;            // 0,1,2
    const float u  = s - cf, um = 1.0f - u;
    const float u2 = u * u, u3 = u2 * u, um3 = um * um * um;
    const float k6 = 0.16666667f;
    const float w0 = um3 * k6;
    const float w1 = (3.0f * u3 - 6.0f * u2 + 4.0f) * k6;
    const float w2 = (-3.0f * u3 + 3.0f * u2 + 3.0f * u + 1.0f) * k6;
    const float w3 = u3 * k6;
    o[0] = f2bf(off == 0 ? w0 : 0.0f);
    o[1] = f2bf(off == 0 ? w1 : (off == 1 ? w0 : 0.0f));
    o[2] = f2bf(off == 0 ? w2 : (off == 1 ? w1 : w0));
    o[3] = f2bf(off == 0 ? w3 : (off == 1 ? w2 : w1));
    o[4] = f2bf(off == 1 ? w3 : (off == 2 ? w2 : 0.0f));
    o[5] = f2bf(off == 2 ? w3 : 0.0f);
}

// ===== Phase 1: pack A and Wt in tiled+swizzled half-tile layout ===========
__global__ __launch_bounds__(256)
void pack_all(const float* __restrict__ x, const float* __restrict__ base_w,
              const float* __restrict__ spline_w, const float* __restrict__ scaler,
              short* __restrict__ A, short* __restrict__ Wt) {
    __shared__ short buf[KD2];          // 14336 B, logical K-order
    const int b = blockIdx.x;
    const int q = threadIdx.x;          // feature quad 0..255 (4 features)
    int row;
    short* mat;

    if (b < BATCH) {                                   // ---- A row
        row = b; mat = A;
        const float4 xv = *(const float4*)&x[(size_t)row * IN_F + q * 4];
        short t[24];
        bases6(xv.x, t + 0);
        bases6(xv.y, t + 6);
        bases6(xv.z, t + 12);
        bases6(xv.w, t + 18);
        *(short8*)&buf[q * 24 + 0]  = *(short8*)(t + 0);
        *(short8*)&buf[q * 24 + 8]  = *(short8*)(t + 8);
        *(short8*)&buf[q * 24 + 16] = *(short8*)(t + 16);
        short4v sl;
        sl[0] = f2bf(silu(xv.x)); sl[1] = f2bf(silu(xv.y));
        sl[2] = f2bf(silu(xv.z)); sl[3] = f2bf(silu(xv.w));
        *(short4v*)&buf[6144 + q * 4] = sl;
    } else {                                           // ---- Wt row
        row = b - BATCH; mat = Wt;
        const int i0 = q * 4;
        short t[24];
#pragma unroll
        for (int f = 0; f < 4; ++f) {
            const size_t idx = (size_t)row * IN_F + i0 + f;
            const float sc = scaler[idx];
            const float4* sw4 = (const float4*)(spline_w + idx * 8);
            const float4 w0 = sw4[0], w1 = sw4[1];     // w0: j0..3, w1: j4..7
            t[f * 6 + 0] = f2bf(w0.z * sc);            // j=2
            t[f * 6 + 1] = f2bf(w0.w * sc);            // j=3
            t[f * 6 + 2] = f2bf(w1.x * sc);            // j=4
            t[f * 6 + 3] = f2bf(w1.y * sc);            // j=5
            t[f * 6 + 4] = f2bf(w1.z * sc);            // j=6
            t[f * 6 + 5] = f2bf(w1.w * sc);            // j=7
        }
        *(short8*)&buf[q * 24 + 0]  = *(short8*)(t + 0);
        *(short8*)&buf[q * 24 + 8]  = *(short8*)(t + 8);
        *(short8*)&buf[q * 24 + 16] = *(short8*)(t + 16);
        const float4 bw = *(const float4*)&base_w[(size_t)row * IN_F + i0];
        short4v bv;
        bv[0] = f2bf(bw.x); bv[1] = f2bf(bw.y);
        bv[2] = f2bf(bw.z); bv[3] = f2bf(bw.w);
        *(short4v*)&buf[6144 + q * 4] = bv;
    }
    __syncthreads();

    // scatter row into tiled+swizzled layout, 16 B granules (896 total)
    const int rowblk = row >> 8;
    const int half   = (row >> 7) & 1;
    const int rl     = row & 127;
    const int sw     = (rl & 7) << 3;
#pragma unroll
    for (int g0 = 0; g0 < 4; ++g0) {
        const int g = q + g0 * 256;
        if (g < 896) {
            const int k0 = g * 8;
            const int kh = (k0 >= KHALF) ? 1 : 0;
            const int kl = k0 - kh * KHALF;
            const int ks = kl >> 6;
            const int col = kl & 63;                   // multiple of 8
            const size_t off = tile_off(rowblk, kh, ks, half)
                             + (size_t)rl * 64 + (col ^ sw);
            *(short8*)&mat[off] = *(const short8*)&buf[k0];
        }
    }
}

// ===== Phase 2: 256x256 8-phase GEMM, split-K=2, counted vmcnt =============
#define GLD_LDS16(gp, lp)                                                     \
    __builtin_amdgcn_global_load_lds(                                         \
        (const __attribute__((address_space(1))) unsigned int*)(gp),          \
        (__attribute__((address_space(3))) unsigned int*)(lp), 16, 0, 0)

// stage one 16 KB half-tile: 2 linear gld_lds per thread (LOADS_PER_HT = 2)
#define STAGE(mat_, ks_, hf_, db_, arr_)                                      \
    { const short* s_ = (mat_) + ((size_t)(ks_) * 2 + (hf_)) * HTSH           \
                        + wave * 1024 + lane * 8;                             \
      GLD_LDS16(s_,       &arr_[db_][hf_][wave * 1024]);                      \
      GLD_LDS16(s_ + 512, &arr_[db_][hf_][wave * 1024 + 512]); }

#define LDA(db_, m_, kf_) (*(const short8*)&As[db_][wr]                       \
    [((m_) * 16 + lrow) * 64 + (((kf_) * 32 + quad * 8) ^ swz)])
#define LDB(db_, n_, kf_) (*(const short8*)&Bs[db_][bhalf]                    \
    [(bro + (n_) * 16 + lrow) * 64 + (((kf_) * 32 + quad * 8) ^ swz)])

#define PH_OPEN                                                               \
    __builtin_amdgcn_s_barrier();                                             \
    asm volatile("s_waitcnt lgkmcnt(0)" ::: "memory");                        \
    __builtin_amdgcn_sched_barrier(0);                                        \
    __builtin_amdgcn_s_setprio(1)
#define PH_CLOSE                                                              \
    __builtin_amdgcn_s_setprio(0);                                            \
    __builtin_amdgcn_s_barrier()
#define PH_CLOSE_VM                                                           \
    __builtin_amdgcn_s_setprio(0);                                            \
    asm volatile("s_waitcnt vmcnt(4)" ::: "memory");                          \
    __builtin_amdgcn_s_barrier()

#define MQ(mh_, nh_)                                                          \
    _Pragma("unroll")                                                         \
    for (int m_ = 0; m_ < 4; ++m_)                                            \
    _Pragma("unroll")                                                         \
    for (int n_ = 0; n_ < 2; ++n_)                                            \
    _Pragma("unroll")                                                         \
    for (int kf_ = 0; kf_ < 2; ++kf_)                                         \
        acc[(mh_) * 4 + m_][(nh_) * 2 + n_] =                                 \
            __builtin_amdgcn_mfma_f32_16x16x32_bf16(                          \
                af[m_][kf_], bf[(nh_) * 2 + n_][kf_],                         \
                acc[(mh_) * 4 + m_][(nh_) * 2 + n_], 0, 0, 0);

__global__ __launch_bounds__(512, 2)
void kan_gemm8(const short* __restrict__ A, const short* __restrict__ Wt,
               float* __restrict__ out0, float* __restrict__ out1) {
    // [dbuf (K-step parity)][half][128x64], 64 KB + 64 KB = 128 KiB
    __shared__ short As[2][2][HTSH];
    __shared__ short Bs[2][2][HTSH];

    // XCD mapping: each XCD owns (kh, cb-pair, rb-half): 2 Wt panels = 3.7 MB
    // (fits 4 MB XCD L2, each reused by 16 rb-blocks); cb-pairs share A tiles.
    const int bid = blockIdx.x;          // 0..255, one block per CU
    const int xcd = bid & 7;
    const int j   = bid >> 3;            // 0..31
    const int kh  = xcd >> 2;
    const int cbp = (xcd >> 1) & 1;
    const int rbh = xcd & 1;
    const int rb  = rbh * 16 + (j >> 1); // 0..31
    const int cb  = cbp * 2 + (j & 1);   // 0..3

    const int tid   = threadIdx.x;
    const int lane  = tid & 63;
    const int wave  = tid >> 6;          // 0..7
    const int wr    = wave & 1;          // M half (= A half-tile index)
    const int wc    = wave >> 1;         // 0..3
    const int bhalf = wc >> 1;           // B half-tile index
    const int bro   = (wc & 1) * 64;     // B row offset within half
    const int lrow  = lane & 15;
    const int quad  = lane >> 4;
    const int swz   = (lrow & 7) << 3;   // T2 swizzle (matches pack)

    const short* Atiles = A  + tile_off(rb, kh, 0, 0);
    const short* Btiles = Wt + tile_off(cb, kh, 0, 0);
    float* __restrict__ outp = kh ? out1 : out0;

    f32x4 acc[8][4];
#pragma unroll
    for (int i = 0; i < 8; ++i)
#pragma unroll
        for (int n = 0; n < 4; ++n) acc[i][n] = (f32x4)0.0f;

    // prologue: buf0 (K-step 0) fully + buf1.B (K-step 1); allow newest 2 HT
    STAGE(Atiles, 0, 0, 0, As);
    STAGE(Atiles, 0, 1, 0, As);
    STAGE(Btiles, 0, 0, 0, Bs);
    STAGE(Btiles, 0, 1, 0, Bs);
    STAGE(Btiles, 1, 0, 1, Bs);
    STAGE(Btiles, 1, 1, 1, Bs);
    asm volatile("s_waitcnt vmcnt(4)" ::: "memory");
    __builtin_amdgcn_s_barrier();

    // 8 phases / iter, 2 K-steps / iter. Stage targets are ≥1 closed phase
    // after the region's last ds_read (race-free); vmcnt(4) only at P3/P7.
    for (int it = 0; it < NKS / 2; ++it) {
        const int k1 = 2 * it + 1;
        int k2 = 2 * it + 2; if (k2 >= NKS) k2 -= NKS;   // tail: harmless re-stage
        int k3 = 2 * it + 3; if (k3 >= NKS) k3 -= NKS;

        short8 af[4][2], bf[4][2];
        // P0: read A-mh0 + B-nh0 (buf0); stage buf1.A0 <- k1
#pragma unroll
        for (int m = 0; m < 4; ++m) { af[m][0] = LDA(0, m, 0); af[m][1] = LDA(0, m, 1); }
#pragma unroll
        for (int n = 0; n < 2; ++n) { bf[n][0] = LDB(0, n, 0); bf[n][1] = LDB(0, n, 1); }
        STAGE(Atiles, k1, 0, 1, As);
        PH_OPEN; MQ(0, 0); PH_CLOSE;
        // P1: read B-nh1 (buf0); stage buf1.A1 <- k1
#pragma unroll
        for (int n = 2; n < 4; ++n) { bf[n][0] = LDB(0, n, 0); bf[n][1] = LDB(0, n, 1); }
        STAGE(Atiles, k1, 1, 1, As);
        PH_OPEN; MQ(0, 1); PH_CLOSE;
        // P2: read A-mh1 (buf0); stage buf0.B0 <- k2 (buf0.B last read at P1)
#pragma unroll
        for (int m = 0; m < 4; ++m) { af[m][0] = LDA(0, m + 4, 0); af[m][1] = LDA(0, m + 4, 1); }
        STAGE(Btiles, k2, 0, 0, Bs);
        PH_OPEN; MQ(1, 1); PH_CLOSE;
        // P3: stage buf0.B1 <- k2; vmcnt(4) guards P4's buf1 reads
        STAGE(Btiles, k2, 1, 0, Bs);
        PH_OPEN; MQ(1, 0); PH_CLOSE_VM;
        // P4: read A-mh0 + B-nh0 (buf1); stage buf0.A0 <- k2 (buf0.A last read P2)
#pragma unroll
        for (int m = 0; m < 4; ++m) { af[m][0] = LDA(1, m, 0); af[m][1] = LDA(1, m, 1); }
#pragma unroll
        for (int n = 0; n < 2; ++n) { bf[n][0] = LDB(1, n, 0); bf[n][1] = LDB(1, n, 1); }
        STAGE(Atiles, k2, 0, 0, As);
        PH_OPEN; MQ(0, 0); PH_CLOSE;
        // P5: read B-nh1 (buf1); stage buf0.A1 <- k2
#pragma unroll
        for (int n = 2; n < 4; ++n) { bf[n][0] = LDB(1, n, 0); bf[n][1] = LDB(1, n, 1); }
        STAGE(Atiles, k2, 1, 0, As);
        PH_OPEN; MQ(0, 1); PH_CLOSE;
        // P6: read A-mh1 (buf1); stage buf1.B0 <- k3 (buf1.B last read P5)
#pragma unroll
        for (int m = 0; m < 4; ++m) { af[m][0] = LDA(1, m + 4, 0); af[m][1] = LDA(1, m + 4, 1); }
        STAGE(Btiles, k3, 0, 1, Bs);
        PH_OPEN; MQ(1, 1); PH_CLOSE;
        // P7: stage buf1.B1 <- k3; vmcnt(4) guards next-iter P0's buf0 reads
        STAGE(Btiles, k3, 1, 1, Bs);
        PH_OPEN; MQ(1, 0); PH_CLOSE_VM;
    }

    // C/D layout: col = lane&15, row = quad*4 + reg (m89-verified)
    const int row0 = rb * 256 + wr * 128;
    const int col0 = cb * 256 + wc * 64;
#pragma unroll
    for (int i = 0; i < 8; ++i)
#pragma unroll
        for (int n = 0; n < 4; ++n)
#pragma unroll
            for (int r = 0; r < 4; ++r)
                outp[(size_t)(row0 + i * 16 + quad * 4 + r) * OUT_F +
                     (col0 + n * 16 + lrow)] = acc[i][n][r];
}

// ===== Phase 3: out += partial ==============================================
__global__ __launch_bounds__(256)
void reduce_add(float* __restrict__ out, const float* __restrict__ part) {
    const size_t i = ((size_t)blockIdx.x * 256 + threadIdx.x) * 4;
    float4 a = *(float4*)&out[i];
    const float4 b = *(const float4*)&part[i];
    a.x += b.x; a.y += b.y; a.z += b.z; a.w += b.w;
    *(float4*)&out[i] = a;
}

// ===== Fused fallback (no workspace) — round-2 kernel, 8-basis layout =======
#define BM 128
#define BN 128
#define STF 40

__device__ __forceinline__ short8 bases8(float xv) {
    const float s  = (xv + 2.2f) * 2.5f;
    const float cf = floorf(s);
    const int   ci = (int)cf;
    const float u  = s - cf, um = 1.0f - u;
    const float u2 = u * u, u3 = u2 * u, um3 = um * um * um;
    const float k6 = 0.16666667f;
    const float w0 = um3 * k6;
    const float w1 = (3.0f * u3 - 6.0f * u2 + 4.0f) * k6;
    const float w2 = (-3.0f * u3 + 3.0f * u2 + 3.0f * u + 1.0f) * k6;
    const float w3 = u3 * k6;
    short8 o;
#pragma unroll
    for (int j = 0; j < 8; ++j) {
        const float v5 = (j == 2) ? w0 : (j == 3) ? w1 : (j == 4) ? w2 : (j == 5) ? w3 : 0.0f;
        const float v6 = (j == 3) ? w0 : (j == 4) ? w1 : (j == 5) ? w2 : (j == 6) ? w3 : 0.0f;
        const float v7 = (j == 4) ? w0 : (j == 5) ? w1 : (j == 6) ? w2 : (j == 7) ? w3 : 0.0f;
        o[j] = f2bf((ci == 5) ? v5 : (ci == 6) ? v6 : v7);
    }
    return o;
}

__global__ __launch_bounds__(256)
void kan_mfma(const float* __restrict__ x,
              const float* __restrict__ base_w,
              const float* __restrict__ spline_w,
              const float* __restrict__ scaler,
              float* __restrict__ out) {
    __shared__ short As2[BM * STF];
    __shared__ short Bs2[BN * STF];

    const int tid  = threadIdx.x;
    const int lane = tid & 63;
    const int wave = tid >> 6;
    const int row0 = blockIdx.y * BM;
    const int col0 = blockIdx.x * BN;
    const int wm0  = (wave & 1) * 64;
    const int wn0  = (wave >> 1) * 64;
    const int lrow = lane & 15;
    const int quad = lane >> 4;

    f32x4 acc[4][4];
#pragma unroll
    for (int i = 0; i < 4; ++i)
#pragma unroll
        for (int j = 0; j < 4; ++j) acc[i][j] = (f32x4)0.0f;

    for (int kc = 0; kc < 256; ++kc) {
        const int fi0 = kc * 4;
#pragma unroll
        for (int it = 0; it < 2; ++it) {
            const int e = tid + it * 256;
            const int r = e >> 2, f = e & 3;
            const float xv = x[(size_t)(row0 + r) * IN_F + fi0 + f];
            *(short8*)&As2[r * STF + f * 8] = bases8(xv);
        }
#pragma unroll
        for (int it = 0; it < 4; ++it) {
            const int idx = tid + it * 256;
            const int c = idx >> 3, qq = idx & 7;
            const int f = qq >> 1;
            const size_t base = ((size_t)(col0 + c) * IN_F + fi0 + f) * 8 + (size_t)(qq & 1) * 4;
            const float4 w = *(const float4*)&spline_w[base];
            const float sc = scaler[(size_t)(col0 + c) * IN_F + fi0 + f];
            short4v o;
            o[0] = f2bf(w.x * sc); o[1] = f2bf(w.y * sc);
            o[2] = f2bf(w.z * sc); o[3] = f2bf(w.w * sc);
            *(short4v*)&Bs2[c * STF + qq * 4] = o;
        }
        __syncthreads();
        short8 a[4], b[4];
#pragma unroll
        for (int i = 0; i < 4; ++i)
            a[i] = *(const short8*)&As2[(wm0 + i * 16 + lrow) * STF + quad * 8];
#pragma unroll
        for (int i = 0; i < 4; ++i)
            b[i] = *(const short8*)&Bs2[(wn0 + i * 16 + lrow) * STF + quad * 8];
#pragma unroll
        for (int i = 0; i < 4; ++i)
#pragma unroll
            for (int j = 0; j < 4; ++j)
                acc[i][j] = __builtin_amdgcn_mfma_f32_16x16x32_bf16(a[i], b[j], acc[i][j], 0, 0, 0);
        __syncthreads();
    }

    for (int sc = 0; sc < 32; ++sc) {
        const int fi0 = sc * 32;
#pragma unroll
        for (int it = 0; it < 4; ++it) {
            const int idx = tid + it * 256;
            const int r = idx >> 3, qq = idx & 7;
            const float4 xv = *(const float4*)&x[(size_t)(row0 + r) * IN_F + fi0 + qq * 4];
            short4v o;
            o[0] = f2bf(silu(xv.x)); o[1] = f2bf(silu(xv.y));
            o[2] = f2bf(silu(xv.z)); o[3] = f2bf(silu(xv.w));
            *(short4v*)&As2[r * STF + qq * 4] = o;
        }
#pragma unroll
        for (int it = 0; it < 4; ++it) {
            const int idx = tid + it * 256;
            const int c = idx >> 3, qq = idx & 7;
            const float4 wv = *(const float4*)&base_w[(size_t)(col0 + c) * IN_F + fi0 + qq * 4];
            short4v o;
            o[0] = f2bf(wv.x); o[1] = f2bf(wv.y);
            o[2] = f2bf(wv.z); o[3] = f2bf(wv.w);
            *(short4v*)&Bs2[c * STF + qq * 4] = o;
        }
        __syncthreads();
        short8 a[4], b[4];
#pragma unroll
        for (int i = 0; i < 4; ++i)
            a[i] = *(const short8*)&As2[(wm0 + i * 16 + lrow) * STF + quad * 8];
#pragma unroll
        for (int i = 0; i < 4; ++i)
            b[i] = *(const short8*)&Bs2[(wn0 + i * 16 + lrow) * STF + quad * 8];
#pragma unroll
        for (int i = 0; i < 4; ++i)
#pragma unroll
            for (int j = 0; j < 4; ++j)
                acc[i][j] = __builtin_amdgcn_mfma_f32_16x16x32_bf16(a[i], b[j], acc[i][j], 0, 0, 0);
        __syncthreads();
    }

#pragma unroll
    for (int i = 0; i < 4; ++i)
#pragma unroll
        for (int j = 0; j < 4; ++j)
#pragma unroll
            for (int r = 0; r < 4; ++r)
                out[(size_t)(row0 + wm0 + i * 16 + quad * 4 + r) * OUT_F +
                    (col0 + wn0 + j * 16 + lrow)] = acc[i][j][r];
}

extern "C" void kernel_launch(void* const* d_in, const int* in_sizes, int n_in,
                              void* d_out, int out_size, void* d_ws, size_t ws_size,
                              hipStream_t stream) {
    const float* x        = (const float*)d_in[0];
    const float* base_w   = (const float*)d_in[1];
    const float* spline_w = (const float*)d_in[2];
    const float* scaler   = (const float*)d_in[3];
    float* out = (float*)d_out;

    const size_t need_A = (size_t)BATCH * KD2 * sizeof(short);   // 117.4 MB
    const size_t need_W = (size_t)OUT_F * KD2 * sizeof(short);   //  14.7 MB
    const size_t need_P = (size_t)BATCH * OUT_F * sizeof(float); //  33.6 MB

    if (ws_size >= need_A + need_W + need_P) {
        short* A  = (short*)d_ws;
        short* Wt = (short*)((char*)d_ws + need_A);
        float* P  = (float*)((char*)d_ws + need_A + need_W);
        pack_all<<<BATCH + OUT_F, 256, 0, stream>>>(x, base_w, spline_w, scaler, A, Wt);
        kan_gemm8<<<256, 512, 0, stream>>>(A, Wt, out, P);
        reduce_add<<<BATCH * OUT_F / 1024, 256, 0, stream>>>(out, P);
    } else {
        dim3 grd(OUT_F / BN, BATCH / BM);
        kan_mfma<<<grd, 256, 0, stream>>>(x, base_w, spline_w, scaler, out);
    }
}

// Round 3
// 247.621 us; speedup vs baseline: 1.1364x; 1.0632x over previous
//
#include <hip/hip_runtime.h>
#include <hip/hip_bf16.h>
#include <math.h>

#define IN_F  1024
#define OUT_F 1024
#define BATCH 8192
#define KD2   7168             // 1024*6 spline (j=2..7) + 1024 silu
#define KHALF 3584             // K per split-K half
#define NKS   56               // K-steps (BK=64) per half
#define HTSH  8192             // shorts per 128x64 half-tile (16 KB)
#define HT2   (2 * HTSH)       // shorts per K-step (32 KB)

typedef short short8  __attribute__((ext_vector_type(8)));
typedef short short4v __attribute__((ext_vector_type(4)));
typedef float f32x4   __attribute__((ext_vector_type(4)));

__device__ __forceinline__ short f2bf(float f) {
    __hip_bfloat16 h = __float2bfloat16(f);   // RNE
    return *reinterpret_cast<short*>(&h);
}

__device__ __forceinline__ float silu(float v) {
    return v / (1.0f + __expf(-v));
}

// Tiled layout: tile (rowblk, kh, ks, half) of 128 rows x 64 k, 16 KB each.
// Within a tile, shorts stored at row*64 + (col ^ ((row&7)<<3))  [T2 swizzle,
// pre-applied at pack time so GEMM staging is pure linear global_load_lds].
__device__ __forceinline__ size_t tile_off(int rowblk, int kh, int ks, int half) {
    return (((((size_t)rowblk * 2 + kh) * NKS + ks) * 2) + half) * (size_t)HTSH;
}

// 6 bases (j=2..7) for one x in [0,1): 4 nonzero at window offset ci-5 in {0,1,2}.
__device__ __forceinline__ void bases6(float xv, short* __restrict__ o) {
    const float s  = (xv + 2.2f) * 2.5f;     // (x - g0) / h
    const float cf = floorf(s);
    const int  off = (int)cf - 5;            // 0,1,2
    const float u  = s - cf, um = 1.0f - u;
    const float u2 = u * u, u3 = u2 * u, um3 = um * um * um;
    const float k6 = 0.16666667f;
    const float w0 = um3 * k6;
    const float w1 = (3.0f * u3 - 6.0f * u2 + 4.0f) * k6;
    const float w2 = (-3.0f * u3 + 3.0f * u2 + 3.0f * u + 1.0f) * k6;
    const float w3 = u3 * k6;
    o[0] = f2bf(off == 0 ? w0 : 0.0f);
    o[1] = f2bf(off == 0 ? w1 : (off == 1 ? w0 : 0.0f));
    o[2] = f2bf(off == 0 ? w2 : (off == 1 ? w1 : w0));
    o[3] = f2bf(off == 0 ? w3 : (off == 1 ? w2 : w1));
    o[4] = f2bf(off == 1 ? w3 : (off == 2 ? w2 : 0.0f));
    o[5] = f2bf(off == 2 ? w3 : 0.0f);
}

// ===== Phase 1: pack A and Wt in tiled+swizzled half-tile layout ===========
__global__ __launch_bounds__(256)
void pack_all(const float* __restrict__ x, const float* __restrict__ base_w,
              const float* __restrict__ spline_w, const float* __restrict__ scaler,
              short* __restrict__ A, short* __restrict__ Wt) {
    __shared__ short buf[KD2];          // 14336 B, logical K-order
    const int b = blockIdx.x;
    const int q = threadIdx.x;          // feature quad 0..255 (4 features)
    int row;
    short* mat;

    if (b < BATCH) {                                   // ---- A row
        row = b; mat = A;
        const float4 xv = *(const float4*)&x[(size_t)row * IN_F + q * 4];
        short t[24];
        bases6(xv.x, t + 0);
        bases6(xv.y, t + 6);
        bases6(xv.z, t + 12);
        bases6(xv.w, t + 18);
        *(short8*)&buf[q * 24 + 0]  = *(short8*)(t + 0);
        *(short8*)&buf[q * 24 + 8]  = *(short8*)(t + 8);
        *(short8*)&buf[q * 24 + 16] = *(short8*)(t + 16);
        short4v sl;
        sl[0] = f2bf(silu(xv.x)); sl[1] = f2bf(silu(xv.y));
        sl[2] = f2bf(silu(xv.z)); sl[3] = f2bf(silu(xv.w));
        *(short4v*)&buf[6144 + q * 4] = sl;
    } else {                                           // ---- Wt row
        row = b - BATCH; mat = Wt;
        const int i0 = q * 4;
        short t[24];
#pragma unroll
        for (int f = 0; f < 4; ++f) {
            const size_t idx = (size_t)row * IN_F + i0 + f;
            const float sc = scaler[idx];
            const float4* sw4 = (const float4*)(spline_w + idx * 8);
            const float4 w0 = sw4[0], w1 = sw4[1];     // w0: j0..3, w1: j4..7
            t[f * 6 + 0] = f2bf(w0.z * sc);            // j=2
            t[f * 6 + 1] = f2bf(w0.w * sc);            // j=3
            t[f * 6 + 2] = f2bf(w1.x * sc);            // j=4
            t[f * 6 + 3] = f2bf(w1.y * sc);            // j=5
            t[f * 6 + 4] = f2bf(w1.z * sc);            // j=6
            t[f * 6 + 5] = f2bf(w1.w * sc);            // j=7
        }
        *(short8*)&buf[q * 24 + 0]  = *(short8*)(t + 0);
        *(short8*)&buf[q * 24 + 8]  = *(short8*)(t + 8);
        *(short8*)&buf[q * 24 + 16] = *(short8*)(t + 16);
        const float4 bw = *(const float4*)&base_w[(size_t)row * IN_F + i0];
        short4v bv;
        bv[0] = f2bf(bw.x); bv[1] = f2bf(bw.y);
        bv[2] = f2bf(bw.z); bv[3] = f2bf(bw.w);
        *(short4v*)&buf[6144 + q * 4] = bv;
    }
    __syncthreads();

    // scatter row into tiled+swizzled layout, 16 B granules (896 total)
    const int rowblk = row >> 8;
    const int half   = (row >> 7) & 1;
    const int rl     = row & 127;
    const int sw     = (rl & 7) << 3;
#pragma unroll
    for (int g0 = 0; g0 < 4; ++g0) {
        const int g = q + g0 * 256;
        if (g < 896) {
            const int k0 = g * 8;
            const int kh = (k0 >= KHALF) ? 1 : 0;
            const int kl = k0 - kh * KHALF;
            const int ks = kl >> 6;
            const int col = kl & 63;                   // multiple of 8
            const size_t off = tile_off(rowblk, kh, ks, half)
                             + (size_t)rl * 64 + (col ^ sw);
            *(short8*)&mat[off] = *(const short8*)&buf[k0];
        }
    }
}

// ===== Phase 2: 256x256 8-phase GEMM, split-K=2, read-shifted pipeline =====
#define GLD_LDS16(gp, lp)                                                     \
    __builtin_amdgcn_global_load_lds(                                         \
        (const __attribute__((address_space(1))) unsigned int*)(gp),          \
        (__attribute__((address_space(3))) unsigned int*)(lp), 16, 0, 0)

// stage one 16 KB half-tile: 2 linear gld_lds per thread
#define STG2(p_, db_, hf_, arr_)                                              \
    GLD_LDS16((p_) + (hf_) * HTSH,       &arr_[db_][hf_][wave * 1024]);       \
    GLD_LDS16((p_) + (hf_) * HTSH + 512, &arr_[db_][hf_][wave * 1024 + 512]);

#define LDA(db_, m_, kf_) (*(const short8*)&As[db_][wr]                       \
    [((m_) * 16 + lrow) * 64 + (((kf_) * 32 + quad * 8) ^ swz)])
#define LDB(db_, n_, kf_) (*(const short8*)&Bs[db_][bhalf]                    \
    [(bro + (n_) * 16 + lrow) * 64 + (((kf_) * 32 + quad * 8) ^ swz)])

// read A-half (8 x ds_read_b128) / B-half (4 x ds_read_b128) into shared banks
#define RD_AMH(mh_, db_) {                                                    \
    _Pragma("unroll")                                                         \
    for (int m_ = 0; m_ < 4; ++m_) {                                          \
        af[m_][0] = LDA(db_, (mh_) * 4 + m_, 0);                              \
        af[m_][1] = LDA(db_, (mh_) * 4 + m_, 1);                              \
    } }
#define RD_BNH(nh_, db_) {                                                    \
    _Pragma("unroll")                                                         \
    for (int n_ = 0; n_ < 2; ++n_) {                                          \
        bf[(nh_) * 2 + n_][0] = LDB(db_, (nh_) * 2 + n_, 0);                  \
        bf[(nh_) * 2 + n_][1] = LDB(db_, (nh_) * 2 + n_, 1);                  \
    } }

#define MQ(mh_, nh_)                                                          \
    _Pragma("unroll")                                                         \
    for (int m_ = 0; m_ < 4; ++m_)                                            \
    _Pragma("unroll")                                                         \
    for (int n_ = 0; n_ < 2; ++n_)                                            \
    _Pragma("unroll")                                                         \
    for (int kf_ = 0; kf_ < 2; ++kf_)                                         \
        acc[(mh_) * 4 + m_][(nh_) * 2 + n_] =                                 \
            __builtin_amdgcn_mfma_f32_16x16x32_bf16(                          \
                af[m_][kf_], bf[(nh_) * 2 + n_][kf_],                         \
                acc[(mh_) * 4 + m_][(nh_) * 2 + n_], 0, 0, 0);

// Raw s_barrier is NOT an IR-level memory fence — bracket it with
// zero-cost compiler fences so the hand-verified phase schedule (stage
// issues and ds_reads pinned to their inter-barrier regions) is preserved.
#define CFENCE asm volatile("" ::: "memory")
#define BAR   do { CFENCE; __builtin_amdgcn_s_barrier(); CFENCE; } while (0)
#define PRIO1 __builtin_amdgcn_s_setprio(1)
#define PRIO0 __builtin_amdgcn_s_setprio(0)
// per-wave vmcnt BEFORE a barrier = cross-wave gate (barrier makes it global)
#define VM4   asm volatile("s_waitcnt vmcnt(4)" ::: "memory")

__global__ __launch_bounds__(512, 2)
void kan_gemm8(const short* __restrict__ A, const short* __restrict__ Wt,
               float* __restrict__ out0, float* __restrict__ out1) {
    // [dbuf (K-step parity)][half][128x64], 64 KB + 64 KB = 128 KiB
    __shared__ short As[2][2][HTSH];
    __shared__ short Bs[2][2][HTSH];

    // XCD mapping: each XCD owns (kh, cb-pair, rb-half): 2 Wt panels = 3.7 MB
    const int bid = blockIdx.x;          // 0..255, one block per CU
    const int xcd = bid & 7;
    const int j   = bid >> 3;            // 0..31
    const int kh  = xcd >> 2;
    const int cbp = (xcd >> 1) & 1;
    const int rbh = xcd & 1;
    const int rb  = rbh * 16 + (j >> 1); // 0..31
    const int cb  = cbp * 2 + (j & 1);   // 0..3

    const int tid   = threadIdx.x;
    const int lane  = tid & 63;
    const int wave  = tid >> 6;          // 0..7
    const int wr    = wave & 1;          // M half (= A half-tile index)
    const int wc    = wave >> 1;         // 0..3
    const int bhalf = wc >> 1;           // B half-tile index
    const int bro   = (wc & 1) * 64;     // B row offset within half
    const int lrow  = lane & 15;
    const int quad  = lane >> 4;
    const int swz   = (lrow & 7) << 3;   // T2 swizzle (matches pack)

    float* __restrict__ outp = kh ? out1 : out0;

    f32x4 acc[8][4];
#pragma unroll
    for (int i = 0; i < 8; ++i)
#pragma unroll
        for (int n = 0; n < 4; ++n) acc[i][n] = (f32x4)0.0f;

    short8 af[4][2], bf[4][2];

    // affine stage pointers (last iter prefetches ≤64KB past each region —
    // provably inside the A|Wt|P workspace, data is dead)
    const short* pA = A  + tile_off(rb, kh, 0, 0) + wave * 1024 + lane * 8;
    const short* pB = Wt + tile_off(cb, kh, 0, 0) + wave * 1024 + lane * 8;

    // prologue: k0 fully (db0) + k1's B (db1) = 12 loads/thread
    STG2(pA, 0, 0, As); STG2(pA, 0, 1, As);
    STG2(pB, 0, 0, Bs); STG2(pB, 0, 1, Bs);
    STG2(pB + HT2, 1, 0, Bs); STG2(pB + HT2, 1, 1, Bs);
    VM4;                          // own k0 loads landed (Bk1 in flight)
    BAR;                          // -> ALL waves' k0 in LDS
    RD_AMH(0, 0); RD_BNH(0, 0);   // pre-reads for P0 (k0)

    // 8 phases / iter, 2 K-steps / iter. All ds_reads live INSIDE the MFMA
    // regions (pre-MQ where no WAR on af/bf; post-MQ where they overwrite the
    // banks MQ consumes). No explicit lgkmcnt: compiler emits fine-grained
    // waits before each consuming MFMA. Race invariants (re-audited):
    //  - every stage issue is >=1 closed phase after the target buffer's
    //    last reader's consuming MFMA (cross-wave via the closing barrier);
    //  - every first read of staged data is behind a VM4+open-barrier pair.
    for (int it = 0; it < NKS / 2; ++it) {
        // P0: MQ(0,0)[k even, db0]; pre-read B-nh1(db0); stage A0<-k1(db1)
        STG2(pA + HT2, 1, 0, As);
        BAR; PRIO1; RD_BNH(1, 0); MQ(0, 0); PRIO0; BAR;
        // P1: MQ(0,1); post-read A-mh1(db0); stage A1<-k1
        STG2(pA + HT2, 1, 1, As);
        BAR; PRIO1; MQ(0, 1); RD_AMH(1, 0); PRIO0; BAR;
        // P2: MQ(1,1); stage B0<-k2(db0)
        STG2(pB + 2 * HT2, 0, 0, Bs);
        BAR; PRIO1; MQ(1, 1); PRIO0; BAR;
        // P3: vmcnt gate (B-k1 db1 + A-k1 landed); MQ(1,0); post-read db1
        STG2(pB + 2 * HT2, 0, 1, Bs);
        VM4;
        BAR; PRIO1; MQ(1, 0); RD_AMH(0, 1); RD_BNH(0, 1); PRIO0; BAR;
        // P4: MQ(0,0)[k odd, db1]; pre-read B-nh1(db1); stage A0<-k2(db0)
        STG2(pA + 2 * HT2, 0, 0, As);
        BAR; PRIO1; RD_BNH(1, 1); MQ(0, 0); PRIO0; BAR;
        // P5: MQ(0,1); post-read A-mh1(db1); stage A1<-k2
        STG2(pA + 2 * HT2, 0, 1, As);
        BAR; PRIO1; MQ(0, 1); RD_AMH(1, 1); PRIO0; BAR;
        // P6: MQ(1,1); stage B0<-k3(db1)
        STG2(pB + 3 * HT2, 1, 0, Bs);
        BAR; PRIO1; MQ(1, 1); PRIO0; BAR;
        // P7: vmcnt gate (B-k2 + A-k2 landed); MQ(1,0); post-read db0 (k2)
        STG2(pB + 3 * HT2, 1, 1, Bs);
        VM4;
        BAR; PRIO1; MQ(1, 0); RD_AMH(0, 0); RD_BNH(0, 0); PRIO0; BAR;
        pA += 2 * HT2; pB += 2 * HT2;
    }

    // C/D layout: col = lane&15, row = quad*4 + reg (m89-verified)
    const int row0 = rb * 256 + wr * 128;
    const int col0 = cb * 256 + wc * 64;
#pragma unroll
    for (int i = 0; i < 8; ++i)
#pragma unroll
        for (int n = 0; n < 4; ++n)
#pragma unroll
            for (int r = 0; r < 4; ++r)
                outp[(size_t)(row0 + i * 16 + quad * 4 + r) * OUT_F +
                     (col0 + n * 16 + lrow)] = acc[i][n][r];
}

// ===== Phase 3: out += partial ==============================================
__global__ __launch_bounds__(256)
void reduce_add(float* __restrict__ out, const float* __restrict__ part) {
    const size_t i = ((size_t)blockIdx.x * 256 + threadIdx.x) * 4;
    float4 a = *(float4*)&out[i];
    const float4 b = *(const float4*)&part[i];
    a.x += b.x; a.y += b.y; a.z += b.z; a.w += b.w;
    *(float4*)&out[i] = a;
}

// ===== Fused fallback (no workspace) — round-2 kernel, 8-basis layout =======
#define BM 128
#define BN 128
#define STF 40

__device__ __forceinline__ short8 bases8(float xv) {
    const float s  = (xv + 2.2f) * 2.5f;
    const float cf = floorf(s);
    const int   ci = (int)cf;
    const float u  = s - cf, um = 1.0f - u;
    const float u2 = u * u, u3 = u2 * u, um3 = um * um * um;
    const float k6 = 0.16666667f;
    const float w0 = um3 * k6;
    const float w1 = (3.0f * u3 - 6.0f * u2 + 4.0f) * k6;
    const float w2 = (-3.0f * u3 + 3.0f * u2 + 3.0f * u + 1.0f) * k6;
    const float w3 = u3 * k6;
    short8 o;
#pragma unroll
    for (int j = 0; j < 8; ++j) {
        const float v5 = (j == 2) ? w0 : (j == 3) ? w1 : (j == 4) ? w2 : (j == 5) ? w3 : 0.0f;
        const float v6 = (j == 3) ? w0 : (j == 4) ? w1 : (j == 5) ? w2 : (j == 6) ? w3 : 0.0f;
        const float v7 = (j == 4) ? w0 : (j == 5) ? w1 : (j == 6) ? w2 : (j == 7) ? w3 : 0.0f;
        o[j] = f2bf((ci == 5) ? v5 : (ci == 6) ? v6 : v7);
    }
    return o;
}

__global__ __launch_bounds__(256)
void kan_mfma(const float* __restrict__ x,
              const float* __restrict__ base_w,
              const float* __restrict__ spline_w,
              const float* __restrict__ scaler,
              float* __restrict__ out) {
    __shared__ short As2[BM * STF];
    __shared__ short Bs2[BN * STF];

    const int tid  = threadIdx.x;
    const int lane = tid & 63;
    const int wave = tid >> 6;
    const int row0 = blockIdx.y * BM;
    const int col0 = blockIdx.x * BN;
    const int wm0  = (wave & 1) * 64;
    const int wn0  = (wave >> 1) * 64;
    const int lrow = lane & 15;
    const int quad = lane >> 4;

    f32x4 acc[4][4];
#pragma unroll
    for (int i = 0; i < 4; ++i)
#pragma unroll
        for (int j = 0; j < 4; ++j) acc[i][j] = (f32x4)0.0f;

    for (int kc = 0; kc < 256; ++kc) {
        const int fi0 = kc * 4;
#pragma unroll
        for (int it = 0; it < 2; ++it) {
            const int e = tid + it * 256;
            const int r = e >> 2, f = e & 3;
            const float xv = x[(size_t)(row0 + r) * IN_F + fi0 + f];
            *(short8*)&As2[r * STF + f * 8] = bases8(xv);
        }
#pragma unroll
        for (int it = 0; it < 4; ++it) {
            const int idx = tid + it * 256;
            const int c = idx >> 3, qq = idx & 7;
            const int f = qq >> 1;
            const size_t base = ((size_t)(col0 + c) * IN_F + fi0 + f) * 8 + (size_t)(qq & 1) * 4;
            const float4 w = *(const float4*)&spline_w[base];
            const float sc = scaler[(size_t)(col0 + c) * IN_F + fi0 + f];
            short4v o;
            o[0] = f2bf(w.x * sc); o[1] = f2bf(w.y * sc);
            o[2] = f2bf(w.z * sc); o[3] = f2bf(w.w * sc);
            *(short4v*)&Bs2[c * STF + qq * 4] = o;
        }
        __syncthreads();
        short8 a[4], b[4];
#pragma unroll
        for (int i = 0; i < 4; ++i)
            a[i] = *(const short8*)&As2[(wm0 + i * 16 + lrow) * STF + quad * 8];
#pragma unroll
        for (int i = 0; i < 4; ++i)
            b[i] = *(const short8*)&Bs2[(wn0 + i * 16 + lrow) * STF + quad * 8];
#pragma unroll
        for (int i = 0; i < 4; ++i)
#pragma unroll
            for (int j = 0; j < 4; ++j)
                acc[i][j] = __builtin_amdgcn_mfma_f32_16x16x32_bf16(a[i], b[j], acc[i][j], 0, 0, 0);
        __syncthreads();
    }

    for (int sc = 0; sc < 32; ++sc) {
        const int fi0 = sc * 32;
#pragma unroll
        for (int it = 0; it < 4; ++it) {
            const int idx = tid + it * 256;
            const int r = idx >> 3, qq = idx & 7;
            const float4 xv = *(const float4*)&x[(size_t)(row0 + r) * IN_F + fi0 + qq * 4];
            short4v o;
            o[0] = f2bf(silu(xv.x)); o[1] = f2bf(silu(xv.y));
            o[2] = f2bf(silu(xv.z)); o[3] = f2bf(silu(xv.w));
            *(short4v*)&As2[r * STF + qq * 4] = o;
        }
#pragma unroll
        for (int it = 0; it < 4; ++it) {
            const int idx = tid + it * 256;
            const int c = idx >> 3, qq = idx & 7;
            const float4 wv = *(const float4*)&base_w[(size_t)(col0 + c) * IN_F + fi0 + qq * 4];
            short4v o;
            o[0] = f2bf(wv.x); o[1] = f2bf(wv.y);
            o[2] = f2bf(wv.z); o[3] = f2bf(wv.w);
            *(short4v*)&Bs2[c * STF + qq * 4] = o;
        }
        __syncthreads();
        short8 a[4], b[4];
#pragma unroll
        for (int i = 0; i < 4; ++i)
            a[i] = *(const short8*)&As2[(wm0 + i * 16 + lrow) * STF + quad * 8];
#pragma unroll
        for (int i = 0; i < 4; ++i)
            b[i] = *(const short8*)&Bs2[(wn0 + i * 16 + lrow) * STF + quad * 8];
#pragma unroll
        for (int i = 0; i < 4; ++i)
#pragma unroll
            for (int j = 0; j < 4; ++j)
                acc[i][j] = __builtin_amdgcn_mfma_f32_16x16x32_bf16(a[i], b[j], acc[i][j], 0, 0, 0);
        __syncthreads();
    }

#pragma unroll
    for (int i = 0; i < 4; ++i)
#pragma unroll
        for (int j = 0; j < 4; ++j)
#pragma unroll
            for (int r = 0; r < 4; ++r)
                out[(size_t)(row0 + wm0 + i * 16 + quad * 4 + r) * OUT_F +
                    (col0 + wn0 + j * 16 + lrow)] = acc[i][j][r];
}

extern "C" void kernel_launch(void* const* d_in, const int* in_sizes, int n_in,
                              void* d_out, int out_size, void* d_ws, size_t ws_size,
                              hipStream_t stream) {
    const float* x        = (const float*)d_in[0];
    const float* base_w   = (const float*)d_in[1];
    const float* spline_w = (const float*)d_in[2];
    const float* scaler   = (const float*)d_in[3];
    float* out = (float*)d_out;

    const size_t need_A = (size_t)BATCH * KD2 * sizeof(short);   // 117.4 MB
    const size_t need_W = (size_t)OUT_F * KD2 * sizeof(short);   //  14.7 MB
    const size_t need_P = (size_t)BATCH * OUT_F * sizeof(float); //  33.6 MB

    if (ws_size >= need_A + need_W + need_P) {
        short* A  = (short*)d_ws;
        short* Wt = (short*)((char*)d_ws + need_A);
        float* P  = (float*)((char*)d_ws + need_A + need_W);
        pack_all<<<BATCH + OUT_F, 256, 0, stream>>>(x, base_w, spline_w, scaler, A, Wt);
        kan_gemm8<<<256, 512, 0, stream>>>(A, Wt, out, P);
        reduce_add<<<BATCH * OUT_F / 1024, 256, 0, stream>>>(out, P);
    } else {
        dim3 grd(OUT_F / BN, BATCH / BM);
        kan_mfma<<<grd, 256, 0, stream>>>(x, base_w, spline_w, scaler, out);
    }
}

// Round 4
// 246.371 us; speedup vs baseline: 1.1422x; 1.0051x over previous
//
#include <hip/hip_runtime.h>
#include <hip/hip_bf16.h>
#include <math.h>

#define IN_F  1024
#define OUT_F 1024
#define BATCH 8192
#define KD2   7168             // 1024*6 spline (j=2..7) + 1024 silu
#define KHALF 3584             // K per split-K half
#define NKS   56               // K-steps (BK=64) per half
#define HTSH  8192             // shorts per 128x64 half-tile (16 KB)
#define HT2   (2 * HTSH)       // shorts per K-step (32 KB)

typedef short short8  __attribute__((ext_vector_type(8)));
typedef short short4v __attribute__((ext_vector_type(4)));
typedef float f32x4   __attribute__((ext_vector_type(4)));

__device__ __forceinline__ short f2bf(float f) {
    __hip_bfloat16 h = __float2bfloat16(f);   // RNE
    return *reinterpret_cast<short*>(&h);
}

__device__ __forceinline__ float silu(float v) {
    return v / (1.0f + __expf(-v));
}

// Tiled layout: tile (rowblk, kh, ks, half) of 128 rows x 64 k, 16 KB each.
// Within a tile, shorts stored at row*64 + (col ^ ((row&7)<<3))  [T2 swizzle,
// pre-applied at pack time so GEMM staging is pure linear global_load_lds].
__device__ __forceinline__ size_t tile_off(int rowblk, int kh, int ks, int half) {
    return (((((size_t)rowblk * 2 + kh) * NKS + ks) * 2) + half) * (size_t)HTSH;
}

// 6 bases (j=2..7) for one x in [0,1): 4 nonzero at window offset ci-5 in {0,1,2}.
__device__ __forceinline__ void bases6(float xv, short* __restrict__ o) {
    const float s  = (xv + 2.2f) * 2.5f;     // (x - g0) / h
    const float cf = floorf(s);
    const int  off = (int)cf - 5;            // 0,1,2
    const float u  = s - cf, um = 1.0f - u;
    const float u2 = u * u, u3 = u2 * u, um3 = um * um * um;
    const float k6 = 0.16666667f;
    const float w0 = um3 * k6;
    const float w1 = (3.0f * u3 - 6.0f * u2 + 4.0f) * k6;
    const float w2 = (-3.0f * u3 + 3.0f * u2 + 3.0f * u + 1.0f) * k6;
    const float w3 = u3 * k6;
    o[0] = f2bf(off == 0 ? w0 : 0.0f);
    o[1] = f2bf(off == 0 ? w1 : (off == 1 ? w0 : 0.0f));
    o[2] = f2bf(off == 0 ? w2 : (off == 1 ? w1 : w0));
    o[3] = f2bf(off == 0 ? w3 : (off == 1 ? w2 : w1));
    o[4] = f2bf(off == 1 ? w3 : (off == 2 ? w2 : 0.0f));
    o[5] = f2bf(off == 2 ? w3 : 0.0f);
}

// ===== Phase 1: pack A and Wt in tiled+swizzled half-tile layout ===========
__global__ __launch_bounds__(256)
void pack_all(const float* __restrict__ x, const float* __restrict__ base_w,
              const float* __restrict__ spline_w, const float* __restrict__ scaler,
              short* __restrict__ A, short* __restrict__ Wt) {
    __shared__ short buf[KD2];          // 14336 B, logical K-order
    const int b = blockIdx.x;
    const int q = threadIdx.x;          // feature quad 0..255 (4 features)
    int row;
    short* mat;

    if (b < BATCH) {                                   // ---- A row
        row = b; mat = A;
        const float4 xv = *(const float4*)&x[(size_t)row * IN_F + q * 4];
        short t[24];
        bases6(xv.x, t + 0);
        bases6(xv.y, t + 6);
        bases6(xv.z, t + 12);
        bases6(xv.w, t + 18);
        *(short8*)&buf[q * 24 + 0]  = *(short8*)(t + 0);
        *(short8*)&buf[q * 24 + 8]  = *(short8*)(t + 8);
        *(short8*)&buf[q * 24 + 16] = *(short8*)(t + 16);
        short4v sl;
        sl[0] = f2bf(silu(xv.x)); sl[1] = f2bf(silu(xv.y));
        sl[2] = f2bf(silu(xv.z)); sl[3] = f2bf(silu(xv.w));
        *(short4v*)&buf[6144 + q * 4] = sl;
    } else {                                           // ---- Wt row
        row = b - BATCH; mat = Wt;
        const int i0 = q * 4;
        short t[24];
#pragma unroll
        for (int f = 0; f < 4; ++f) {
            const size_t idx = (size_t)row * IN_F + i0 + f;
            const float sc = scaler[idx];
            const float4* sw4 = (const float4*)(spline_w + idx * 8);
            const float4 w0 = sw4[0], w1 = sw4[1];     // w0: j0..3, w1: j4..7
            t[f * 6 + 0] = f2bf(w0.z * sc);            // j=2
            t[f * 6 + 1] = f2bf(w0.w * sc);            // j=3
            t[f * 6 + 2] = f2bf(w1.x * sc);            // j=4
            t[f * 6 + 3] = f2bf(w1.y * sc);            // j=5
            t[f * 6 + 4] = f2bf(w1.z * sc);            // j=6
            t[f * 6 + 5] = f2bf(w1.w * sc);            // j=7
        }
        *(short8*)&buf[q * 24 + 0]  = *(short8*)(t + 0);
        *(short8*)&buf[q * 24 + 8]  = *(short8*)(t + 8);
        *(short8*)&buf[q * 24 + 16] = *(short8*)(t + 16);
        const float4 bw = *(const float4*)&base_w[(size_t)row * IN_F + i0];
        short4v bv;
        bv[0] = f2bf(bw.x); bv[1] = f2bf(bw.y);
        bv[2] = f2bf(bw.z); bv[3] = f2bf(bw.w);
        *(short4v*)&buf[6144 + q * 4] = bv;
    }
    __syncthreads();

    // scatter row into tiled+swizzled layout, 16 B granules (896 total)
    const int rowblk = row >> 8;
    const int half   = (row >> 7) & 1;
    const int rl     = row & 127;
    const int sw     = (rl & 7) << 3;
#pragma unroll
    for (int g0 = 0; g0 < 4; ++g0) {
        const int g = q + g0 * 256;
        if (g < 896) {
            const int k0 = g * 8;
            const int kh = (k0 >= KHALF) ? 1 : 0;
            const int kl = k0 - kh * KHALF;
            const int ks = kl >> 6;
            const int col = kl & 63;                   // multiple of 8
            const size_t off = tile_off(rowblk, kh, ks, half)
                             + (size_t)rl * 64 + (col ^ sw);
            *(short8*)&mat[off] = *(const short8*)&buf[k0];
        }
    }
}

// ===== Phase 2: 256x256 GEMM, split-K=2, 32-MFMA merged phases =============
#define GLD_LDS16(gp, lp)                                                     \
    __builtin_amdgcn_global_load_lds(                                         \
        (const __attribute__((address_space(1))) unsigned int*)(gp),          \
        (__attribute__((address_space(3))) unsigned int*)(lp), 16, 0, 0)

// stage one 16 KB half-tile: 2 linear gld_lds per thread
#define STG2(p_, db_, hf_, arr_)                                              \
    GLD_LDS16((p_) + (hf_) * HTSH,       &arr_[db_][hf_][wave * 1024]);       \
    GLD_LDS16((p_) + (hf_) * HTSH + 512, &arr_[db_][hf_][wave * 1024 + 512]);

// stage a full 32 KB K-step tile (both halves, 4 loads/thread)
#define STG4(p_, db_, arr_)                                                   \
    STG2(p_, db_, 0, arr_); STG2(p_, db_, 1, arr_);

#define LDA(db_, m_, kf_) (*(const short8*)&As[db_][wr]                       \
    [((m_) * 16 + lrow) * 64 + (((kf_) * 32 + quad * 8) ^ swz)])
#define LDB(db_, n_, kf_) (*(const short8*)&Bs[db_][bhalf]                    \
    [(bro + (n_) * 16 + lrow) * 64 + (((kf_) * 32 + quad * 8) ^ swz)])

// refill af with one A M-half (8 ds_read_b128) / bf with all B n-frags (8)
#define RD_A(mh_, db_) {                                                      \
    _Pragma("unroll")                                                         \
    for (int m_ = 0; m_ < 4; ++m_) {                                          \
        af[m_][0] = LDA(db_, (mh_) * 4 + m_, 0);                              \
        af[m_][1] = LDA(db_, (mh_) * 4 + m_, 1);                              \
    } }
#define RD_B(db_) {                                                           \
    _Pragma("unroll")                                                         \
    for (int n_ = 0; n_ < 4; ++n_) {                                          \
        bf[n_][0] = LDB(db_, n_, 0);                                          \
        bf[n_][1] = LDB(db_, n_, 1);                                          \
    } }

// one M-half x all 4 N-frags x kf0,1 = 32 MFMA (acc row offset mo_)
#define MQ32(mo_)                                                             \
    _Pragma("unroll")                                                         \
    for (int m_ = 0; m_ < 4; ++m_)                                            \
    _Pragma("unroll")                                                         \
    for (int n_ = 0; n_ < 4; ++n_)                                            \
    _Pragma("unroll")                                                         \
    for (int kf_ = 0; kf_ < 2; ++kf_)                                         \
        acc[(mo_) + m_][n_] = __builtin_amdgcn_mfma_f32_16x16x32_bf16(        \
            af[m_][kf_], bf[n_][kf_], acc[(mo_) + m_][n_], 0, 0, 0);

// Raw s_barrier is NOT an IR-level memory fence — bracket it with
// zero-cost compiler fences so stage issues / ds_reads stay pinned to
// their inter-barrier regions.
#define CFENCE asm volatile("" ::: "memory")
#define BAR   do { CFENCE; __builtin_amdgcn_s_barrier(); CFENCE; } while (0)
#define PRIO1 __builtin_amdgcn_s_setprio(1)
#define PRIO0 __builtin_amdgcn_s_setprio(0)
// per-wave vmcnt BEFORE a barrier = cross-wave gate (barrier makes it global)
#define VM4   asm volatile("s_waitcnt vmcnt(4)" ::: "memory")
#define VM8   asm volatile("s_waitcnt vmcnt(8)" ::: "memory")

__global__ __launch_bounds__(512, 2)
void kan_gemm8(const short* __restrict__ A, const short* __restrict__ Wt,
               float* __restrict__ out0, float* __restrict__ out1) {
    // [dbuf (K-step parity)][half][128x64], 64 KB + 64 KB = 128 KiB
    __shared__ short As[2][2][HTSH];
    __shared__ short Bs[2][2][HTSH];

    // XCD mapping: each XCD owns (kh, cb-pair, rb-half): 2 Wt panels = 3.7 MB
    const int bid = blockIdx.x;          // 0..255, one block per CU
    const int xcd = bid & 7;
    const int j   = bid >> 3;            // 0..31
    const int kh  = xcd >> 2;
    const int cbp = (xcd >> 1) & 1;
    const int rbh = xcd & 1;
    const int rb  = rbh * 16 + (j >> 1); // 0..31
    const int cb  = cbp * 2 + (j & 1);   // 0..3

    const int tid   = threadIdx.x;
    const int lane  = tid & 63;
    const int wave  = tid >> 6;          // 0..7
    const int wr    = wave & 1;          // M half (= A half-tile index)
    const int wc    = wave >> 1;         // 0..3
    const int bhalf = wc >> 1;           // B half-tile index
    const int bro   = (wc & 1) * 64;     // B row offset within half
    const int lrow  = lane & 15;
    const int quad  = lane >> 4;
    const int swz   = (lrow & 7) << 3;   // T2 swizzle (matches pack)

    float* __restrict__ outp = kh ? out1 : out0;

    f32x4 acc[8][4];
#pragma unroll
    for (int i = 0; i < 8; ++i)
#pragma unroll
        for (int n = 0; n < 4; ++n) acc[i][n] = (f32x4)0.0f;

    // single register banks (VGPR budget: acc 128 AGPR + frags 64 VGPR)
    short8 af[4][2], bf[4][2];

    // affine stage pointers (tail prefetches ≤96 KB past each region —
    // provably inside the A|Wt|P workspace, data is dead)
    const short* pA = A  + tile_off(rb, kh, 0, 0) + wave * 1024 + lane * 8;
    const short* pB = Wt + tile_off(cb, kh, 0, 0) + wave * 1024 + lane * 8;

    // prologue: A(0),B(0)->db0; A(1),B(1)->db1 (16 loads/thread)
    STG4(pA, 0, As);
    STG4(pB, 0, Bs);
    STG4(pA + HT2, 1, As);
    STG4(pB + HT2, 1, Bs);
    VM8;                          // A(0),B(0) landed; A(1),B(1) in flight
    BAR;                          // -> ALL waves' k0 in LDS
    RD_A(0, 0); RD_B(0);          // af<-A(0)mh0, bf<-B(0)

    // 2 phases / K-step, 32 MFMA per barrier-pair. Post-MQ reads reuse the
    // same af/bf banks (WAR on registers orders them after the consuming
    // MFMAs); their consumers sit one closed phase later, so LDS latency
    // hides across the barrier. VM4 ledger at each PhB: outstanding =
    // {B(k+1), A(k+1), B(k+2)} = 12 -> retires exactly A/B(k+1) (the data
    // this phase's post-reads touch), leaves B(k+2) in flight.
    for (int it = 0; it < NKS / 2; ++it) {
        // PhA(k): stage B(k+2)->db0 | MQ(mh0, k) | read af<-A(k)mh1
        STG4(pB + 2 * HT2, 0, Bs);
        BAR; PRIO1; MQ32(0); RD_A(1, 0); PRIO0; BAR;
        // PhB(k): VM4; stage A(k+2)->db0 | MQ(mh1, k) | read A(k+1)mh0+B(k+1)
        VM4;
        STG4(pA + 2 * HT2, 0, As);
        BAR; PRIO1; MQ32(4); RD_A(0, 1); RD_B(1); PRIO0; BAR;
        // PhA(k+1): stage B(k+3)->db1 | MQ(mh0, k+1) | read af<-A(k+1)mh1
        STG4(pB + 3 * HT2, 1, Bs);
        BAR; PRIO1; MQ32(0); RD_A(1, 1); PRIO0; BAR;
        // PhB(k+1): VM4; stage A(k+3)->db1 | MQ(mh1, k+1) | read k+2 (db0)
        VM4;
        STG4(pA + 3 * HT2, 1, As);
        BAR; PRIO1; MQ32(4); RD_A(0, 0); RD_B(0); PRIO0; BAR;
        pA += 2 * HT2; pB += 2 * HT2;
    }

    // C/D layout: col = lane&15, row = quad*4 + reg (m89-verified)
    const int row0 = rb * 256 + wr * 128;
    const int col0 = cb * 256 + wc * 64;
#pragma unroll
    for (int i = 0; i < 8; ++i)
#pragma unroll
        for (int n = 0; n < 4; ++n)
#pragma unroll
            for (int r = 0; r < 4; ++r)
                outp[(size_t)(row0 + i * 16 + quad * 4 + r) * OUT_F +
                     (col0 + n * 16 + lrow)] = acc[i][n][r];
}

// ===== Phase 3: out += partial ==============================================
__global__ __launch_bounds__(256)
void reduce_add(float* __restrict__ out, const float* __restrict__ part) {
    const size_t i = ((size_t)blockIdx.x * 256 + threadIdx.x) * 4;
    float4 a = *(float4*)&out[i];
    const float4 b = *(const float4*)&part[i];
    a.x += b.x; a.y += b.y; a.z += b.z; a.w += b.w;
    *(float4*)&out[i] = a;
}

// ===== Fused fallback (no workspace) — round-2 kernel, 8-basis layout =======
#define BM 128
#define BN 128
#define STF 40

__device__ __forceinline__ short8 bases8(float xv) {
    const float s  = (xv + 2.2f) * 2.5f;
    const float cf = floorf(s);
    const int   ci = (int)cf;
    const float u  = s - cf, um = 1.0f - u;
    const float u2 = u * u, u3 = u2 * u, um3 = um * um * um;
    const float k6 = 0.16666667f;
    const float w0 = um3 * k6;
    const float w1 = (3.0f * u3 - 6.0f * u2 + 4.0f) * k6;
    const float w2 = (-3.0f * u3 + 3.0f * u2 + 3.0f * u + 1.0f) * k6;
    const float w3 = u3 * k6;
    short8 o;
#pragma unroll
    for (int j = 0; j < 8; ++j) {
        const float v5 = (j == 2) ? w0 : (j == 3) ? w1 : (j == 4) ? w2 : (j == 5) ? w3 : 0.0f;
        const float v6 = (j == 3) ? w0 : (j == 4) ? w1 : (j == 5) ? w2 : (j == 6) ? w3 : 0.0f;
        const float v7 = (j == 4) ? w0 : (j == 5) ? w1 : (j == 6) ? w2 : (j == 7) ? w3 : 0.0f;
        o[j] = f2bf((ci == 5) ? v5 : (ci == 6) ? v6 : v7);
    }
    return o;
}

__global__ __launch_bounds__(256)
void kan_mfma(const float* __restrict__ x,
              const float* __restrict__ base_w,
              const float* __restrict__ spline_w,
              const float* __restrict__ scaler,
              float* __restrict__ out) {
    __shared__ short As2[BM * STF];
    __shared__ short Bs2[BN * STF];

    const int tid  = threadIdx.x;
    const int lane = tid & 63;
    const int wave = tid >> 6;
    const int row0 = blockIdx.y * BM;
    const int col0 = blockIdx.x * BN;
    const int wm0  = (wave & 1) * 64;
    const int wn0  = (wave >> 1) * 64;
    const int lrow = lane & 15;
    const int quad = lane >> 4;

    f32x4 acc[4][4];
#pragma unroll
    for (int i = 0; i < 4; ++i)
#pragma unroll
        for (int j = 0; j < 4; ++j) acc[i][j] = (f32x4)0.0f;

    for (int kc = 0; kc < 256; ++kc) {
        const int fi0 = kc * 4;
#pragma unroll
        for (int it = 0; it < 2; ++it) {
            const int e = tid + it * 256;
            const int r = e >> 2, f = e & 3;
            const float xv = x[(size_t)(row0 + r) * IN_F + fi0 + f];
            *(short8*)&As2[r * STF + f * 8] = bases8(xv);
        }
#pragma unroll
        for (int it = 0; it < 4; ++it) {
            const int idx = tid + it * 256;
            const int c = idx >> 3, qq = idx & 7;
            const int f = qq >> 1;
            const size_t base = ((size_t)(col0 + c) * IN_F + fi0 + f) * 8 + (size_t)(qq & 1) * 4;
            const float4 w = *(const float4*)&spline_w[base];
            const float sc = scaler[(size_t)(col0 + c) * IN_F + fi0 + f];
            short4v o;
            o[0] = f2bf(w.x * sc); o[1] = f2bf(w.y * sc);
            o[2] = f2bf(w.z * sc); o[3] = f2bf(w.w * sc);
            *(short4v*)&Bs2[c * STF + qq * 4] = o;
        }
        __syncthreads();
        short8 a[4], b[4];
#pragma unroll
        for (int i = 0; i < 4; ++i)
            a[i] = *(const short8*)&As2[(wm0 + i * 16 + lrow) * STF + quad * 8];
#pragma unroll
        for (int i = 0; i < 4; ++i)
            b[i] = *(const short8*)&Bs2[(wn0 + i * 16 + lrow) * STF + quad * 8];
#pragma unroll
        for (int i = 0; i < 4; ++i)
#pragma unroll
            for (int j = 0; j < 4; ++j)
                acc[i][j] = __builtin_amdgcn_mfma_f32_16x16x32_bf16(a[i], b[j], acc[i][j], 0, 0, 0);
        __syncthreads();
    }

    for (int sc = 0; sc < 32; ++sc) {
        const int fi0 = sc * 32;
#pragma unroll
        for (int it = 0; it < 4; ++it) {
            const int idx = tid + it * 256;
            const int r = idx >> 3, qq = idx & 7;
            const float4 xv = *(const float4*)&x[(size_t)(row0 + r) * IN_F + fi0 + qq * 4];
            short4v o;
            o[0] = f2bf(silu(xv.x)); o[1] = f2bf(silu(xv.y));
            o[2] = f2bf(silu(xv.z)); o[3] = f2bf(silu(xv.w));
            *(short4v*)&As2[r * STF + qq * 4] = o;
        }
#pragma unroll
        for (int it = 0; it < 4; ++it) {
            const int idx = tid + it * 256;
            const int c = idx >> 3, qq = idx & 7;
            const float4 wv = *(const float4*)&base_w[(size_t)(col0 + c) * IN_F + fi0 + qq * 4];
            short4v o;
            o[0] = f2bf(wv.x); o[1] = f2bf(wv.y);
            o[2] = f2bf(wv.z); o[3] = f2bf(wv.w);
            *(short4v*)&Bs2[c * STF + qq * 4] = o;
        }
        __syncthreads();
        short8 a[4], b[4];
#pragma unroll
        for (int i = 0; i < 4; ++i)
            a[i] = *(const short8*)&As2[(wm0 + i * 16 + lrow) * STF + quad * 8];
#pragma unroll
        for (int i = 0; i < 4; ++i)
            b[i] = *(const short8*)&Bs2[(wn0 + i * 16 + lrow) * STF + quad * 8];
#pragma unroll
        for (int i = 0; i < 4; ++i)
#pragma unroll
            for (int j = 0; j < 4; ++j)
                acc[i][j] = __builtin_amdgcn_mfma_f32_16x16x32_bf16(a[i], b[j], acc[i][j], 0, 0, 0);
        __syncthreads();
    }

#pragma unroll
    for (int i = 0; i < 4; ++i)
#pragma unroll
        for (int j = 0; j < 4; ++j)
#pragma unroll
            for (int r = 0; r < 4; ++r)
                out[(size_t)(row0 + wm0 + i * 16 + quad * 4 + r) * OUT_F +
                    (col0 + wn0 + j * 16 + lrow)] = acc[i][j][r];
}

extern "C" void kernel_launch(void* const* d_in, const int* in_sizes, int n_in,
                              void* d_out, int out_size, void* d_ws, size_t ws_size,
                              hipStream_t stream) {
    const float* x        = (const float*)d_in[0];
    const float* base_w   = (const float*)d_in[1];
    const float* spline_w = (const float*)d_in[2];
    const float* scaler   = (const float*)d_in[3];
    float* out = (float*)d_out;

    const size_t need_A = (size_t)BATCH * KD2 * sizeof(short);   // 117.4 MB
    const size_t need_W = (size_t)OUT_F * KD2 * sizeof(short);   //  14.7 MB
    const size_t need_P = (size_t)BATCH * OUT_F * sizeof(float); //  33.6 MB

    if (ws_size >= need_A + need_W + need_P) {
        short* A  = (short*)d_ws;
        short* Wt = (short*)((char*)d_ws + need_A);
        float* P  = (float*)((char*)d_ws + need_A + need_W);
        pack_all<<<BATCH + OUT_F, 256, 0, stream>>>(x, base_w, spline_w, scaler, A, Wt);
        kan_gemm8<<<256, 512, 0, stream>>>(A, Wt, out, P);
        reduce_add<<<BATCH * OUT_F / 1024, 256, 0, stream>>>(out, P);
    } else {
        dim3 grd(OUT_F / BN, BATCH / BM);
        kan_mfma<<<grd, 256, 0, stream>>>(x, base_w, spline_w, scaler, out);
    }
}

// Round 6
// 242.229 us; speedup vs baseline: 1.1617x; 1.0171x over previous
//
#include <hip/hip_runtime.h>
#include <hip/hip_bf16.h>
#include <math.h>

#define IN_F  1024
#define OUT_F 1024
#define BATCH 8192
#define KD2   7168             // 1024*6 spline (j=2..7) + 1024 silu
#define KHALF 3584             // K per split-K half
#define NKS   56               // K-steps (BK=64) per half
#define HTSH  8192             // shorts per 128x64 half-tile (16 KB)
#define HT2   (2 * HTSH)       // shorts per K-step (32 KB)

typedef short short8  __attribute__((ext_vector_type(8)));
typedef short short4v __attribute__((ext_vector_type(4)));
typedef float f32x4   __attribute__((ext_vector_type(4)));

__device__ __forceinline__ short f2bf(float f) {
    __hip_bfloat16 h = __float2bfloat16(f);   // RNE
    return *reinterpret_cast<short*>(&h);
}

__device__ __forceinline__ float silu(float v) {
    return v / (1.0f + __expf(-v));
}

// Tiled layout: tile (rowblk, kh, ks, half) of 128 rows x 64 k, 16 KB each.
// Within a tile, shorts stored at row*64 + (col ^ ((row&7)<<3))  [T2 swizzle,
// pre-applied at pack time so GEMM staging is pure linear global_load_lds].
__device__ __forceinline__ size_t tile_off(int rowblk, int kh, int ks, int half) {
    return (((((size_t)rowblk * 2 + kh) * NKS + ks) * 2) + half) * (size_t)HTSH;
}

// 6 bases (j=2..7) for one x in [0,1): 4 nonzero at window offset ci-5 in {0,1,2}.
__device__ __forceinline__ void bases6(float xv, short* __restrict__ o) {
    const float s  = (xv + 2.2f) * 2.5f;     // (x - g0) / h
    const float cf = floorf(s);
    const int  off = (int)cf - 5;            // 0,1,2
    const float u  = s - cf, um = 1.0f - u;
    const float u2 = u * u, u3 = u2 * u, um3 = um * um * um;
    const float k6 = 0.16666667f;
    const float w0 = um3 * k6;
    const float w1 = (3.0f * u3 - 6.0f * u2 + 4.0f) * k6;
    const float w2 = (-3.0f * u3 + 3.0f * u2 + 3.0f * u + 1.0f) * k6;
    const float w3 = u3 * k6;
    o[0] = f2bf(off == 0 ? w0 : 0.0f);
    o[1] = f2bf(off == 0 ? w1 : (off == 1 ? w0 : 0.0f));
    o[2] = f2bf(off == 0 ? w2 : (off == 1 ? w1 : w0));
    o[3] = f2bf(off == 0 ? w3 : (off == 1 ? w2 : w1));
    o[4] = f2bf(off == 1 ? w3 : (off == 2 ? w2 : 0.0f));
    o[5] = f2bf(off == 2 ? w3 : 0.0f);
}

// ===== Phase 1: pack A and Wt in tiled+swizzled half-tile layout ===========
__global__ __launch_bounds__(256)
void pack_all(const float* __restrict__ x, const float* __restrict__ base_w,
              const float* __restrict__ spline_w, const float* __restrict__ scaler,
              short* __restrict__ A, short* __restrict__ Wt) {
    __shared__ short buf[KD2];          // 14336 B, logical K-order
    const int b = blockIdx.x;
    const int q = threadIdx.x;          // feature quad 0..255 (4 features)
    int row;
    short* mat;

    if (b < BATCH) {                                   // ---- A row
        row = b; mat = A;
        const float4 xv = *(const float4*)&x[(size_t)row * IN_F + q * 4];
        short t[24];
        bases6(xv.x, t + 0);
        bases6(xv.y, t + 6);
        bases6(xv.z, t + 12);
        bases6(xv.w, t + 18);
        *(short8*)&buf[q * 24 + 0]  = *(short8*)(t + 0);
        *(short8*)&buf[q * 24 + 8]  = *(short8*)(t + 8);
        *(short8*)&buf[q * 24 + 16] = *(short8*)(t + 16);
        short4v sl;
        sl[0] = f2bf(silu(xv.x)); sl[1] = f2bf(silu(xv.y));
        sl[2] = f2bf(silu(xv.z)); sl[3] = f2bf(silu(xv.w));
        *(short4v*)&buf[6144 + q * 4] = sl;
    } else {                                           // ---- Wt row
        row = b - BATCH; mat = Wt;
        const int i0 = q * 4;
        short t[24];
#pragma unroll
        for (int f = 0; f < 4; ++f) {
            const size_t idx = (size_t)row * IN_F + i0 + f;
            const float sc = scaler[idx];
            const float4* sw4 = (const float4*)(spline_w + idx * 8);
            const float4 w0 = sw4[0], w1 = sw4[1];     // w0: j0..3, w1: j4..7
            t[f * 6 + 0] = f2bf(w0.z * sc);            // j=2
            t[f * 6 + 1] = f2bf(w0.w * sc);            // j=3
            t[f * 6 + 2] = f2bf(w1.x * sc);            // j=4
            t[f * 6 + 3] = f2bf(w1.y * sc);            // j=5
            t[f * 6 + 4] = f2bf(w1.z * sc);            // j=6
            t[f * 6 + 5] = f2bf(w1.w * sc);            // j=7
        }
        *(short8*)&buf[q * 24 + 0]  = *(short8*)(t + 0);
        *(short8*)&buf[q * 24 + 8]  = *(short8*)(t + 8);
        *(short8*)&buf[q * 24 + 16] = *(short8*)(t + 16);
        const float4 bw = *(const float4*)&base_w[(size_t)row * IN_F + i0];
        short4v bv;
        bv[0] = f2bf(bw.x); bv[1] = f2bf(bw.y);
        bv[2] = f2bf(bw.z); bv[3] = f2bf(bw.w);
        *(short4v*)&buf[6144 + q * 4] = bv;
    }
    __syncthreads();

    // scatter row into tiled+swizzled layout, 16 B granules (896 total)
    const int rowblk = row >> 8;
    const int half   = (row >> 7) & 1;
    const int rl     = row & 127;
    const int sw     = (rl & 7) << 3;
#pragma unroll
    for (int g0 = 0; g0 < 4; ++g0) {
        const int g = q + g0 * 256;
        if (g < 896) {
            const int k0 = g * 8;
            const int kh = (k0 >= KHALF) ? 1 : 0;
            const int kl = k0 - kh * KHALF;
            const int ks = kl >> 6;
            const int col = kl & 63;                   // multiple of 8
            const size_t off = tile_off(rowblk, kh, ks, half)
                             + (size_t)rl * 64 + (col ^ sw);
            *(short8*)&mat[off] = *(const short8*)&buf[k0];
        }
    }
}

// ===== Phase 2: 256x256 GEMM, split-K=2, read-interleaved 32-MFMA phases ===
#define GLD_LDS16(gp, lp)                                                     \
    __builtin_amdgcn_global_load_lds(                                         \
        (const __attribute__((address_space(1))) unsigned int*)(gp),          \
        (__attribute__((address_space(3))) unsigned int*)(lp), 16, 0, 0)

// stage one 16 KB half-tile: 2 linear gld_lds per thread
#define STG2(p_, db_, hf_, arr_)                                              \
    GLD_LDS16((p_) + (hf_) * HTSH,       &arr_[db_][hf_][wave * 1024]);       \
    GLD_LDS16((p_) + (hf_) * HTSH + 512, &arr_[db_][hf_][wave * 1024 + 512]);

// stage a full 32 KB K-step tile (both halves, 4 loads/thread)
#define STG4(p_, db_, arr_)                                                   \
    STG2(p_, db_, 0, arr_); STG2(p_, db_, 1, arr_);

#define LDA(db_, m_, kf_) (*(const short8*)&As[db_][wr]                       \
    [((m_) * 16 + lrow) * 64 + (((kf_) * 32 + quad * 8) ^ swz)])
#define LDB(db_, n_, kf_) (*(const short8*)&Bs[db_][bhalf]                    \
    [(bro + (n_) * 16 + lrow) * 64 + (((kf_) * 32 + quad * 8) ^ swz)])

// refill one af bank (2 x ds_read_b128) / one kf-slice of bf (4 reads)
#define RDA1(m_, mh_, db_) {                                                  \
    af[m_][0] = LDA(db_, (mh_) * 4 + (m_), 0);                                \
    af[m_][1] = LDA(db_, (mh_) * 4 + (m_), 1); }
#define RDBK(db_, kf_) {                                                      \
    _Pragma("unroll")                                                         \
    for (int n_ = 0; n_ < 4; ++n_) bf[n_][kf_] = LDB(db_, n_, kf_); }

// 16 MFMA: all (m,n) at one kf (acc row offset mo_)
#define MQ16(mo_, kf_)                                                        \
    _Pragma("unroll")                                                         \
    for (int m_ = 0; m_ < 4; ++m_)                                            \
    _Pragma("unroll")                                                         \
    for (int n_ = 0; n_ < 4; ++n_)                                            \
        acc[(mo_) + m_][n_] = __builtin_amdgcn_mfma_f32_16x16x32_bf16(        \
            af[m_][kf_], bf[n_][kf_], acc[(mo_) + m_][n_], 0, 0, 0);

// 4 MFMA: one m, all n, one kf
#define MQ4(mo_, m_, kf_)                                                     \
    _Pragma("unroll")                                                         \
    for (int n_ = 0; n_ < 4; ++n_)                                            \
        acc[(mo_) + (m_)][n_] = __builtin_amdgcn_mfma_f32_16x16x32_bf16(      \
            af[m_][kf_], bf[n_][kf_], acc[(mo_) + (m_)][n_], 0, 0, 0);

// Raw s_barrier is NOT an IR-level memory fence — bracket it with
// zero-cost compiler fences so stage issues / ds_reads stay pinned to
// their inter-barrier regions.
#define CFENCE asm volatile("" ::: "memory")
#define BAR   do { CFENCE; __builtin_amdgcn_s_barrier(); CFENCE; } while (0)
#define SB    __builtin_amdgcn_sched_barrier(0)
#define PRIO1 __builtin_amdgcn_s_setprio(1)
#define PRIO0 __builtin_amdgcn_s_setprio(0)
// per-wave vmcnt BEFORE a barrier = cross-wave gate (barrier makes it global)
#define VM4   asm volatile("s_waitcnt vmcnt(4)" ::: "memory")
#define VM8   asm volatile("s_waitcnt vmcnt(8)" ::: "memory")

// PhA(k): compute mh0 (acc rows 0-3). Reads spread through kf1 half:
// af[m] dies after its kf1 quad -> refill af <- A(k)mh1 immediately.
// Accumulation per acc element stays kf0-then-kf1 (bit-identical).
#define PHA(d_, stgB_)                                                        \
    STG4(stgB_, d_, Bs);                                                      \
    BAR; PRIO1;                                                               \
    MQ16(0, 0);                                                               \
    SB; MQ4(0, 0, 1); SB; RDA1(0, 1, d_);                                     \
    SB; MQ4(0, 1, 1); SB; RDA1(1, 1, d_);                                     \
    SB; MQ4(0, 2, 1); SB; RDA1(2, 1, d_);                                     \
    SB; MQ4(0, 3, 1); SB; RDA1(3, 1, d_);                                     \
    PRIO0; BAR

// PhB(k): compute mh1 (acc rows 4-7). bf[*][kf0] dies after the kf0 half ->
// refill mid-cluster from B(k+1); af banks refill to A(k+1)mh0 during kf1;
// bf[*][kf1] refills at tail. VM4 ledger: outstanding at gate =
// {B(k+1),A(k+1),B(k+2)} = 12 -> retires exactly A/B(k+1), leaves B(k+2).
#define PHB(d_, stgA_)                                                        \
    VM4;                                                                      \
    STG4(stgA_, d_, As);                                                      \
    BAR; PRIO1;                                                               \
    MQ16(4, 0);                                                               \
    SB; RDBK((d_) ^ 1, 0);                                                    \
    SB; MQ4(4, 0, 1); SB; RDA1(0, 0, (d_) ^ 1);                               \
    SB; MQ4(4, 1, 1); SB; RDA1(1, 0, (d_) ^ 1);                               \
    SB; MQ4(4, 2, 1); SB; RDA1(2, 0, (d_) ^ 1);                               \
    SB; MQ4(4, 3, 1); SB; RDA1(3, 0, (d_) ^ 1);                               \
    SB; RDBK((d_) ^ 1, 1);                                                    \
    PRIO0; BAR

__global__ __launch_bounds__(512, 2)
void kan_gemm8(const short* __restrict__ A, const short* __restrict__ Wt,
               float* __restrict__ out0, float* __restrict__ out1) {
    // [dbuf (K-step parity)][half][128x64], 64 KB + 64 KB = 128 KiB
    __shared__ short As[2][2][HTSH];
    __shared__ short Bs[2][2][HTSH];

    // XCD mapping: each XCD owns (kh, cb-pair, rb-half): 2 Wt panels = 3.7 MB
    const int bid = blockIdx.x;          // 0..255, one block per CU
    const int xcd = bid & 7;
    const int j   = bid >> 3;            // 0..31
    const int kh  = xcd >> 2;
    const int cbp = (xcd >> 1) & 1;
    const int rbh = xcd & 1;
    const int rb  = rbh * 16 + (j >> 1); // 0..31
    const int cb  = cbp * 2 + (j & 1);   // 0..3

    const int tid   = threadIdx.x;
    const int lane  = tid & 63;
    const int wave  = tid >> 6;          // 0..7
    const int wr    = wave & 1;          // M half (= A half-tile index)
    const int wc    = wave >> 1;         // 0..3
    const int bhalf = wc >> 1;           // B half-tile index
    const int bro   = (wc & 1) * 64;     // B row offset within half
    const int lrow  = lane & 15;
    const int quad  = lane >> 4;
    const int swz   = (lrow & 7) << 3;   // T2 swizzle (matches pack)

    float* __restrict__ outp = kh ? out1 : out0;

    f32x4 acc[8][4];
#pragma unroll
    for (int i = 0; i < 8; ++i)
#pragma unroll
        for (int n = 0; n < 4; ++n) acc[i][n] = (f32x4)0.0f;

    // single register banks (budget: acc 128 AGPR + frags 64 VGPR)
    short8 af[4][2], bf[4][2];

    // affine stage pointers (tail prefetches ≤96 KB past each region —
    // provably inside the A|Wt|P workspace, data is dead)
    const short* pA = A  + tile_off(rb, kh, 0, 0) + wave * 1024 + lane * 8;
    const short* pB = Wt + tile_off(cb, kh, 0, 0) + wave * 1024 + lane * 8;

    // prologue: A(0),B(0)->db0; A(1),B(1)->db1 (16 loads/thread)
    STG4(pA, 0, As);
    STG4(pB, 0, Bs);
    STG4(pA + HT2, 1, As);
    STG4(pB + HT2, 1, Bs);
    VM8;                          // A(0),B(0) landed; A(1),B(1) in flight
    BAR;                          // -> ALL waves' k0 in LDS
    RDA1(0, 0, 0); RDA1(1, 0, 0); RDA1(2, 0, 0); RDA1(3, 0, 0);
    RDBK(0, 0); RDBK(0, 1);       // af<-A(0)mh0, bf<-B(0)

    for (int it = 0; it < NKS / 2; ++it) {
        PHA(0, pB + 2 * HT2);     // k even: stage B(k+2)->db0
        PHB(0, pA + 2 * HT2);     //          stage A(k+2)->db0
        PHA(1, pB + 3 * HT2);     // k odd:  stage B(k+3)->db1
        PHB(1, pA + 3 * HT2);     //          stage A(k+3)->db1
        pA += 2 * HT2; pB += 2 * HT2;
    }

    // C/D layout: col = lane&15, row = quad*4 + reg (m89-verified)
    const int row0 = rb * 256 + wr * 128;
    const int col0 = cb * 256 + wc * 64;
#pragma unroll
    for (int i = 0; i < 8; ++i)
#pragma unroll
        for (int n = 0; n < 4; ++n)
#pragma unroll
            for (int r = 0; r < 4; ++r)
                outp[(size_t)(row0 + i * 16 + quad * 4 + r) * OUT_F +
                     (col0 + n * 16 + lrow)] = acc[i][n][r];
}

// ===== Phase 3: out += partial ==============================================
__global__ __launch_bounds__(256)
void reduce_add(float* __restrict__ out, const float* __restrict__ part) {
    const size_t i = ((size_t)blockIdx.x * 256 + threadIdx.x) * 4;
    float4 a = *(float4*)&out[i];
    const float4 b = *(const float4*)&part[i];
    a.x += b.x; a.y += b.y; a.z += b.z; a.w += b.w;
    *(float4*)&out[i] = a;
}

// ===== Fused fallback (no workspace) — round-2 kernel, 8-basis layout =======
#define BM 128
#define BN 128
#define STF 40

__device__ __forceinline__ short8 bases8(float xv) {
    const float s  = (xv + 2.2f) * 2.5f;
    const float cf = floorf(s);
    const int   ci = (int)cf;
    const float u  = s - cf, um = 1.0f - u;
    const float u2 = u * u, u3 = u2 * u, um3 = um * um * um;
    const float k6 = 0.16666667f;
    const float w0 = um3 * k6;
    const float w1 = (3.0f * u3 - 6.0f * u2 + 4.0f) * k6;
    const float w2 = (-3.0f * u3 + 3.0f * u2 + 3.0f * u + 1.0f) * k6;
    const float w3 = u3 * k6;
    short8 o;
#pragma unroll
    for (int j = 0; j < 8; ++j) {
        const float v5 = (j == 2) ? w0 : (j == 3) ? w1 : (j == 4) ? w2 : (j == 5) ? w3 : 0.0f;
        const float v6 = (j == 3) ? w0 : (j == 4) ? w1 : (j == 5) ? w2 : (j == 6) ? w3 : 0.0f;
        const float v7 = (j == 4) ? w0 : (j == 5) ? w1 : (j == 6) ? w2 : (j == 7) ? w3 : 0.0f;
        o[j] = f2bf((ci == 5) ? v5 : (ci == 6) ? v6 : v7);
    }
    return o;
}

__global__ __launch_bounds__(256)
void kan_mfma(const float* __restrict__ x,
              const float* __restrict__ base_w,
              const float* __restrict__ spline_w,
              const float* __restrict__ scaler,
              float* __restrict__ out) {
    __shared__ short As2[BM * STF];
    __shared__ short Bs2[BN * STF];

    const int tid  = threadIdx.x;
    const int lane = tid & 63;
    const int wave = tid >> 6;
    const int row0 = blockIdx.y * BM;
    const int col0 = blockIdx.x * BN;
    const int wm0  = (wave & 1) * 64;
    const int wn0  = (wave >> 1) * 64;
    const int lrow = lane & 15;
    const int quad = lane >> 4;

    f32x4 acc[4][4];
#pragma unroll
    for (int i = 0; i < 4; ++i)
#pragma unroll
        for (int j = 0; j < 4; ++j) acc[i][j] = (f32x4)0.0f;

    for (int kc = 0; kc < 256; ++kc) {
        const int fi0 = kc * 4;
#pragma unroll
        for (int it = 0; it < 2; ++it) {
            const int e = tid + it * 256;
            const int r = e >> 2, f = e & 3;
            const float xv = x[(size_t)(row0 + r) * IN_F + fi0 + f];
            *(short8*)&As2[r * STF + f * 8] = bases8(xv);
        }
#pragma unroll
        for (int it = 0; it < 4; ++it) {
            const int idx = tid + it * 256;
            const int c = idx >> 3, qq = idx & 7;
            const int f = qq >> 1;
            const size_t base = ((size_t)(col0 + c) * IN_F + fi0 + f) * 8 + (size_t)(qq & 1) * 4;
            const float4 w = *(const float4*)&spline_w[base];
            const float sc = scaler[(size_t)(col0 + c) * IN_F + fi0 + f];
            short4v o;
            o[0] = f2bf(w.x * sc); o[1] = f2bf(w.y * sc);
            o[2] = f2bf(w.z * sc); o[3] = f2bf(w.w * sc);
            *(short4v*)&Bs2[c * STF + qq * 4] = o;
        }
        __syncthreads();
        short8 a[4], b[4];
#pragma unroll
        for (int i = 0; i < 4; ++i)
            a[i] = *(const short8*)&As2[(wm0 + i * 16 + lrow) * STF + quad * 8];
#pragma unroll
        for (int i = 0; i < 4; ++i)
            b[i] = *(const short8*)&Bs2[(wn0 + i * 16 + lrow) * STF + quad * 8];
#pragma unroll
        for (int i = 0; i < 4; ++i)
#pragma unroll
            for (int j = 0; j < 4; ++j)
                acc[i][j] = __builtin_amdgcn_mfma_f32_16x16x32_bf16(a[i], b[j], acc[i][j], 0, 0, 0);
        __syncthreads();
    }

    for (int sc = 0; sc < 32; ++sc) {
        const int fi0 = sc * 32;
#pragma unroll
        for (int it = 0; it < 4; ++it) {
            const int idx = tid + it * 256;
            const int r = idx >> 3, qq = idx & 7;
            const float4 xv = *(const float4*)&x[(size_t)(row0 + r) * IN_F + fi0 + qq * 4];
            short4v o;
            o[0] = f2bf(silu(xv.x)); o[1] = f2bf(silu(xv.y));
            o[2] = f2bf(silu(xv.z)); o[3] = f2bf(silu(xv.w));
            *(short4v*)&As2[r * STF + qq * 4] = o;
        }
#pragma unroll
        for (int it = 0; it < 4; ++it) {
            const int idx = tid + it * 256;
            const int c = idx >> 3, qq = idx & 7;
            const float4 wv = *(const float4*)&base_w[(size_t)(col0 + c) * IN_F + fi0 + qq * 4];
            short4v o;
            o[0] = f2bf(wv.x); o[1] = f2bf(wv.y);
            o[2] = f2bf(wv.z); o[3] = f2bf(wv.w);
            *(short4v*)&Bs2[c * STF + qq * 4] = o;
        }
        __syncthreads();
        short8 a[4], b[4];
#pragma unroll
        for (int i = 0; i < 4; ++i)
            a[i] = *(const short8*)&As2[(wm0 + i * 16 + lrow) * STF + quad * 8];
#pragma unroll
        for (int i = 0; i < 4; ++i)
            b[i] = *(const short8*)&Bs2[(wn0 + i * 16 + lrow) * STF + quad * 8];
#pragma unroll
        for (int i = 0; i < 4; ++i)
#pragma unroll
            for (int j = 0; j < 4; ++j)
                acc[i][j] = __builtin_amdgcn_mfma_f32_16x16x32_bf16(a[i], b[j], acc[i][j], 0, 0, 0);
        __syncthreads();
    }

#pragma unroll
    for (int i = 0; i < 4; ++i)
#pragma unroll
        for (int j = 0; j < 4; ++j)
#pragma unroll
            for (int r = 0; r < 4; ++r)
                out[(size_t)(row0 + wm0 + i * 16 + quad * 4 + r) * OUT_F +
                    (col0 + wn0 + j * 16 + lrow)] = acc[i][j][r];
}

extern "C" void kernel_launch(void* const* d_in, const int* in_sizes, int n_in,
                              void* d_out, int out_size, void* d_ws, size_t ws_size,
                              hipStream_t stream) {
    const float* x        = (const float*)d_in[0];
    const float* base_w   = (const float*)d_in[1];
    const float* spline_w = (const float*)d_in[2];
    const float* scaler   = (const float*)d_in[3];
    float* out = (float*)d_out;

    const size_t need_A = (size_t)BATCH * KD2 * sizeof(short);   // 117.4 MB
    const size_t need_W = (size_t)OUT_F * KD2 * sizeof(short);   //  14.7 MB
    const size_t need_P = (size_t)BATCH * OUT_F * sizeof(float); //  33.6 MB

    if (ws_size >= need_A + need_W + need_P) {
        short* A  = (short*)d_ws;
        short* Wt = (short*)((char*)d_ws + need_A);
        float* P  = (float*)((char*)d_ws + need_A + need_W);
        pack_all<<<BATCH + OUT_F, 256, 0, stream>>>(x, base_w, spline_w, scaler, A, Wt);
        kan_gemm8<<<256, 512, 0, stream>>>(A, Wt, out, P);
        reduce_add<<<BATCH * OUT_F / 1024, 256, 0, stream>>>(out, P);
    } else {
        dim3 grd(OUT_F / BN, BATCH / BM);
        kan_mfma<<<grd, 256, 0, stream>>>(x, base_w, spline_w, scaler, out);
    }
}